// Round 11
// baseline (3723.157 us; speedup 1.0000x reference)
//
#include <hip/hip_runtime.h>
#include <stdint.h>

#define NSEQ 512
#define EPS 1e-5f
#define WSP_BYTES 122880   // 120 frags * 1024 B; params (f32) follow

// param offsets (floats)
#define P_B0 0
#define P_G0 128
#define P_E0 256
#define P_B1 384
#define P_G1 512
#define P_E1 640
#define P_B2 768
#define P_G2 896
#define P_E2 1024
#define P_BO 1152
// frag bases (shorts)
#define F_A0Z 0
#define F_A0C (16*512)
#define F_A1  (40*512)
#define F_A2  (72*512)
#define F_AO  (104*512)

typedef short bfrag __attribute__((ext_vector_type(8)));
typedef float f4 __attribute__((ext_vector_type(4)));
#define MFMA16 __builtin_amdgcn_mfma_f32_16x16x32_bf16

__device__ __forceinline__ unsigned short f2bf(float f){
  uint32_t u = __float_as_uint(f);
  u += 0x7FFFu + ((u>>16)&1u);   // RNE
  return (unsigned short)(u>>16);
}
__device__ __forceinline__ uint32_t pk2bf(float a, float b){
  uint32_t r;
  asm("v_cvt_pk_bf16_f32 %0, %1, %2" : "=v"(r) : "v"(a), "v"(b));
  return r;
}
__device__ __forceinline__ float tanh_fast(float v){
  float e = __builtin_amdgcn_exp2f(v * 2.8853900817779268f);  // e^(2v)
  float r = __builtin_amdgcn_rcpf(e + 1.f);
  return fmaf(-2.f, r, 1.f);
}

// ---------------- prep kernel: gather permuted bf16 weight frags + params into ws
__global__ void ode_prep(const float* __restrict__ W0, const float* __restrict__ W1,
                         const float* __restrict__ W2, const float* __restrict__ Wo,
                         const float* __restrict__ b0, const float* __restrict__ g0, const float* __restrict__ e0,
                         const float* __restrict__ b1, const float* __restrict__ g1, const float* __restrict__ e1,
                         const float* __restrict__ b2, const float* __restrict__ g2, const float* __restrict__ e2,
                         const float* __restrict__ bo, void* __restrict__ ws)
{
  const int f = blockIdx.x, l = threadIdx.x, lg = l>>4, lc = l&15;
  short* wsA = (short*)ws;
  float* wsP = (float*)((char*)ws + WSP_BYTES);
  if (f < 120){
    union { unsigned short u[8]; uint4 q; } r;
    if (f < 16){                       // A0Z: z-part of W0, zeta-permuted rows
      const int t = f>>1, kt = f&1;
#pragma unroll
      for (int j=0;j<8;++j){
        const int row = 16*(2*kt + (j>>2)) + 4*lg + (j&3);
        r.u[j] = f2bf(W0[(size_t)row*128 + 16*t + lc]);
      }
    } else if (f < 40){                // A0C: cond-part of W0, natural rows
      const int g = f-16, t = g/3, c = g - 3*t;
#pragma unroll
      for (int j=0;j<8;++j){
        const int row = 64 + c*32 + lg*8 + j;
        r.u[j] = f2bf(W0[(size_t)row*128 + 16*t + lc]);
      }
    } else if (f < 72){                // A1: pi-permuted
      const int g = f-40, t = g>>2, kt = g&3;
#pragma unroll
      for (int j=0;j<8;++j){
        const int row = 16*(2*kt + (j>>2)) + 4*lg + (j&3);
        r.u[j] = f2bf(W1[(size_t)row*128 + 16*t + lc]);
      }
    } else if (f < 104){               // A2
      const int g = f-72, t = g>>2, kt = g&3;
#pragma unroll
      for (int j=0;j<8;++j){
        const int row = 16*(2*kt + (j>>2)) + 4*lg + (j&3);
        r.u[j] = f2bf(W2[(size_t)row*128 + 16*t + lc]);
      }
    } else {                           // AO: Wo (ld 64), pi-permuted
      const int g = f-104, t = g>>2, kt = g&3;
#pragma unroll
      for (int j=0;j<8;++j){
        const int row = 16*(2*kt + (j>>2)) + 4*lg + (j&3);
        r.u[j] = f2bf(Wo[(size_t)row*64 + 16*t + lc]);
      }
    }
    *(uint4*)(wsA + (size_t)f*512 + l*8) = r.q;
  } else {
    for (int idx=l; idx<1216; idx+=64){
      const int a = idx>>7, rr = idx&127;
      float v;
      switch(a){
        case 0: v=b0[rr]; break; case 1: v=g0[rr]; break; case 2: v=e0[rr]; break;
        case 3: v=b1[rr]; break; case 4: v=g1[rr]; break; case 5: v=e1[rr]; break;
        case 6: v=b2[rr]; break; case 7: v=g2[rr]; break; case 8: v=e2[rr]; break;
        default: v=bo[idx-1152]; break;
      }
      wsP[idx]=v;
    }
  }
}

// LN + tanh + pack: acc (8 tiles x f4) -> B[4]; stats via 4 in-wave shuffles only
__device__ __forceinline__ void ln_pack(f4 (&acc)[8], const float* __restrict__ gp,
                                        const float* __restrict__ ep, bfrag (&B)[4]){
  float s=0.f, q=0.f;
#pragma unroll
  for (int t=0;t<8;++t){
    s += (acc[t][0]+acc[t][1]) + (acc[t][2]+acc[t][3]);
    q += fmaf(acc[t][0],acc[t][0], acc[t][1]*acc[t][1])
       + fmaf(acc[t][2],acc[t][2], acc[t][3]*acc[t][3]);
  }
  s += __shfl_xor(s,16); q += __shfl_xor(q,16);
  s += __shfl_xor(s,32); q += __shfl_xor(q,32);
  const float mu = s*0.0078125f;
  const float rs = rsqrtf(fmaf(q,0.0078125f,-mu*mu)+EPS);
#pragma unroll
  for (int t=0;t<8;++t){
    const f4 gg = *(const f4*)(gp + 16*t);
    const f4 bb = *(const f4*)(ep + 16*t);
#pragma unroll
    for (int g=0; g<4; ++g)
      acc[t][g] = tanh_fast(fmaf((acc[t][g]-mu)*rs, gg[g], bb[g]));
  }
  union { bfrag v; uint32_t u[4]; } r;
#pragma unroll
  for (int kt=0;kt<4;++kt){
    r.u[0]=pk2bf(acc[2*kt][0],  acc[2*kt][1]);
    r.u[1]=pk2bf(acc[2*kt][2],  acc[2*kt][3]);
    r.u[2]=pk2bf(acc[2*kt+1][0],acc[2*kt+1][1]);
    r.u[3]=pk2bf(acc[2*kt+1][2],acc[2*kt+1][3]);
    B[kt]=r.v;
  }
}

__device__ __forceinline__ void cvt_cond(const f4 (&cf)[6], bfrag (&Bc)[3]){
  union { bfrag v; uint32_t u[4]; } r;
#pragma unroll
  for (int c=0;c<3;++c){
    r.u[0]=pk2bf(cf[2*c][0],cf[2*c][1]);
    r.u[1]=pk2bf(cf[2*c][2],cf[2*c][3]);
    r.u[2]=pk2bf(cf[2*c+1][0],cf[2*c+1][1]);
    r.u[3]=pk2bf(cf[2*c+1][2],cf[2*c+1][3]);
    Bc[c]=r.v;
  }
}

__global__ __launch_bounds__(64,1)
void ode_step(const short* __restrict__ wf, const float* __restrict__ wp,
              const float* __restrict__ z0, const float* __restrict__ tt,
              const float* __restrict__ cond, float* __restrict__ out)
{
  const int l = threadIdx.x, lg = l>>4, lc = l&15;
  const int r0 = blockIdx.x*16;

  // time pipeline
  const float* tp = tt + (size_t)(r0+lc)*NSEQ;
  float tcv = tp[0], tnv = tp[1];

  // z in registers: zr[t][g] = z[batch lc][16t+4lg+g]; pack Bz; write out step 0
  f4 zr[4];
  bfrag Bz0, Bz1;
  {
    const float* zp = z0 + (size_t)(r0+lc)*64 + 4*lg;
    float* op = out + ((size_t)(r0+lc)*NSEQ)*64 + 4*lg;
#pragma unroll
    for (int t=0;t<4;++t){
      zr[t] = *(const f4*)(zp + 16*t);
      *(f4*)(op + 16*t) = zr[t];
    }
    union { bfrag v; uint32_t u[4]; } a, b;
    a.u[0]=pk2bf(zr[0][0],zr[0][1]); a.u[1]=pk2bf(zr[0][2],zr[0][3]);
    a.u[2]=pk2bf(zr[1][0],zr[1][1]); a.u[3]=pk2bf(zr[1][2],zr[1][3]);
    b.u[0]=pk2bf(zr[2][0],zr[2][1]); b.u[1]=pk2bf(zr[2][2],zr[2][3]);
    b.u[2]=pk2bf(zr[3][0],zr[3][1]); b.u[3]=pk2bf(zr[3][2],zr[3][3]);
    Bz0=a.v; Bz1=b.v;
  }

  // cond pointer for this lane
  const float* cb = cond + ((size_t)(r0+lc)*NSEQ)*96 + lg*8;
  f4 cf[6];
#pragma unroll
  for (int c=0;c<3;++c){
    cf[2*c]   = *(const f4*)(cb + c*32);
    cf[2*c+1] = *(const f4*)(cb + c*32 + 4);
  }

  // prologue: apC(0) = bias0 + cond(0) @ W0c
  f4 apC[8];
  {
    bfrag Bc[3];
    cvt_cond(cf, Bc);
    const short* wf0 = wf + l*8;
    const float* wp0 = wp + 4*lg;
#pragma unroll
    for (int t=0;t<8;++t) apC[t] = *(const f4*)(wp0 + P_B0 + 16*t);
#pragma unroll
    for (int c=0;c<3;++c)
#pragma unroll
      for (int t=0;t<8;++t){
        const bfrag a = *(const bfrag*)(wf0 + F_A0C + (t*3+c)*512);
        apC[t] = MFMA16(a, Bc[c], apC[t],0,0,0);
      }
  }
  // cf <- cond(1)
#pragma unroll
  for (int c=0;c<3;++c){
    cf[2*c]   = *(const f4*)(cb + 96 + c*32);
    cf[2*c+1] = *(const f4*)(cb + 96 + c*32 + 4);
  }

  int iz = 0;
  for (int i=0; i<NSEQ-1; ++i){
    asm("" : "+v"(iz));                       // defeat LICM of frag/param loads
    const short* wfi = wf + l*8 + iz;
    const float* wpi = wp + 4*lg + iz;

    // ---- L0: z MFMAs into apC (which holds bias0 + cond(i))
#pragma unroll
    for (int t=0;t<8;++t){
      const bfrag a = *(const bfrag*)(wfi + F_A0Z + (t*2+0)*512);
      apC[t] = MFMA16(a, Bz0, apC[t],0,0,0);
    }
#pragma unroll
    for (int t=0;t<8;++t){
      const bfrag a = *(const bfrag*)(wfi + F_A0Z + (t*2+1)*512);
      apC[t] = MFMA16(a, Bz1, apC[t],0,0,0);
    }
    bfrag B[4];
    ln_pack(apC, wpi + P_G0, wpi + P_E0, B);

    // ---- L1
    f4 acc[8];
#pragma unroll
    for (int t=0;t<8;++t) acc[t] = *(const f4*)(wpi + P_B1 + 16*t);
#pragma unroll
    for (int kt=0;kt<4;++kt)
#pragma unroll
      for (int t=0;t<8;++t){
        const bfrag a = *(const bfrag*)(wfi + F_A1 + (t*4+kt)*512);
        acc[t] = MFMA16(a, B[kt], acc[t],0,0,0);
      }
    ln_pack(acc, wpi + P_G1, wpi + P_E1, B);

    // ---- rebuild apC for step i+1: bias0 + cond(i+1) @ W0c (overlaps LN phases)
    {
      bfrag Bc[3];
      cvt_cond(cf, Bc);
#pragma unroll
      for (int t=0;t<8;++t) apC[t] = *(const f4*)(wpi + P_B0 + 16*t);
#pragma unroll
      for (int c=0;c<3;++c)
#pragma unroll
        for (int t=0;t<8;++t){
          const bfrag a = *(const bfrag*)(wfi + F_A0C + (t*3+c)*512);
          apC[t] = MFMA16(a, Bc[c], apC[t],0,0,0);
        }
      const int ic = (i < NSEQ-2) ? (i+2) : (NSEQ-1);
      const float* cbi = cb + (size_t)ic*96;
#pragma unroll
      for (int c=0;c<3;++c){
        cf[2*c]   = *(const f4*)(cbi + c*32);
        cf[2*c+1] = *(const f4*)(cbi + c*32 + 4);
      }
    }

    // ---- L2
#pragma unroll
    for (int t=0;t<8;++t) acc[t] = *(const f4*)(wpi + P_B2 + 16*t);
#pragma unroll
    for (int kt=0;kt<4;++kt)
#pragma unroll
      for (int t=0;t<8;++t){
        const bfrag a = *(const bfrag*)(wfi + F_A2 + (t*4+kt)*512);
        acc[t] = MFMA16(a, B[kt], acc[t],0,0,0);
      }
    ln_pack(acc, wpi + P_G2, wpi + P_E2, B);

    // ---- Lo + Euler + store + z re-pack
    {
      f4 ao[4];
#pragma unroll
      for (int t=0;t<4;++t) ao[t] = *(const f4*)(wpi + P_BO + 16*t);
#pragma unroll
      for (int kt=0;kt<4;++kt)
#pragma unroll
        for (int t=0;t<4;++t){
          const bfrag a = *(const bfrag*)(wfi + F_AO + (t*4+kt)*512);
          ao[t] = MFMA16(a, B[kt], ao[t],0,0,0);
        }
      const int ip2 = (i < NSEQ-2) ? (i+2) : (NSEQ-1);
      const float tfv = tp[ip2];
      const float dt = tnv - tcv;
      float* op = out + ((size_t)(r0+lc)*NSEQ + (size_t)(i+1))*64 + 4*lg;
#pragma unroll
      for (int t=0;t<4;++t){
#pragma unroll
        for (int g=0;g<4;++g) zr[t][g] = fmaf(dt, ao[t][g], zr[t][g]);
        *(f4*)(op + 16*t) = zr[t];
      }
      union { bfrag v; uint32_t u[4]; } a, b;
      a.u[0]=pk2bf(zr[0][0],zr[0][1]); a.u[1]=pk2bf(zr[0][2],zr[0][3]);
      a.u[2]=pk2bf(zr[1][0],zr[1][1]); a.u[3]=pk2bf(zr[1][2],zr[1][3]);
      b.u[0]=pk2bf(zr[2][0],zr[2][1]); b.u[1]=pk2bf(zr[2][2],zr[2][3]);
      b.u[2]=pk2bf(zr[3][0],zr[3][1]); b.u[3]=pk2bf(zr[3][2],zr[3][3]);
      Bz0=a.v; Bz1=b.v;
      tcv = tnv; tnv = tfv;
    }
  }
}

extern "C" void kernel_launch(void* const* d_in, const int* in_sizes, int n_in,
                              void* d_out, int out_size, void* d_ws, size_t ws_size,
                              hipStream_t stream) {
  const float* z0   = (const float*)d_in[0];
  const float* tt   = (const float*)d_in[1];
  const float* cond = (const float*)d_in[2];
  const float* W0   = (const float*)d_in[3];
  const float* b0   = (const float*)d_in[4];
  const float* g0   = (const float*)d_in[5];
  const float* be0  = (const float*)d_in[6];
  const float* W1   = (const float*)d_in[7];
  const float* b1   = (const float*)d_in[8];
  const float* g1   = (const float*)d_in[9];
  const float* be1  = (const float*)d_in[10];
  const float* W2   = (const float*)d_in[11];
  const float* b2   = (const float*)d_in[12];
  const float* g2   = (const float*)d_in[13];
  const float* be2  = (const float*)d_in[14];
  const float* Wo   = (const float*)d_in[15];
  const float* bo   = (const float*)d_in[16];
  float* out = (float*)d_out;

  hipLaunchKernelGGL(ode_prep, dim3(121), dim3(64), 0, stream,
                     W0, W1, W2, Wo, b0, g0, be0, b1, g1, be1,
                     b2, g2, be2, bo, d_ws);
  hipLaunchKernelGGL(ode_step, dim3(64), dim3(64), 0, stream,
                     (const short*)d_ws, (const float*)((const char*)d_ws + WSP_BYTES),
                     z0, tt, cond, out);
}

// Round 12
// 2361.010 us; speedup vs baseline: 1.5769x; 1.5769x over previous
//
#include <hip/hip_runtime.h>
#include <stdint.h>

#define NSEQ 512
#define EPS 1e-5f
#define WSP_BYTES 122880   // 120 frags * 1024 B in ws; params (f32) follow

// ws frag bases (shorts)
#define F_A0Z 0
#define F_A0C (16*512)
#define F_A1  (40*512)
#define F_A2  (72*512)
#define F_AO  (104*512)

// LDS layout: frags A0C(24), A1(32), A2(32) then params
#define L_A0C 0
#define L_A1  (24*512)
#define L_A2  (56*512)
#define L_FRAG_SHORTS (88*512)
#define L_TOTAL_BYTES (L_FRAG_SHORTS*2 + 4864)   // 90112 + 4864 = 94976

// param offsets (floats)
#define P_B0 0
#define P_G0 128
#define P_E0 256
#define P_B1 384
#define P_G1 512
#define P_E1 640
#define P_B2 768
#define P_G2 896
#define P_E2 1024
#define P_BO 1152

typedef short bfrag __attribute__((ext_vector_type(8)));
typedef float f4 __attribute__((ext_vector_type(4)));
#define MFMA16 __builtin_amdgcn_mfma_f32_16x16x32_bf16

__device__ __forceinline__ unsigned short f2bf(float f){
  uint32_t u = __float_as_uint(f);
  u += 0x7FFFu + ((u>>16)&1u);   // RNE
  return (unsigned short)(u>>16);
}
__device__ __forceinline__ uint32_t pk2bf(float a, float b){
  uint32_t r;
  asm("v_cvt_pk_bf16_f32 %0, %1, %2" : "=v"(r) : "v"(a), "v"(b));
  return r;
}
__device__ __forceinline__ float tanh_fast(float v){
  float e = __builtin_amdgcn_exp2f(v * 2.8853900817779268f);  // e^(2v)
  float r = __builtin_amdgcn_rcpf(e + 1.f);
  return fmaf(-2.f, r, 1.f);
}

// ---------------- prep kernel (verified in R11): permuted bf16 frags + params -> ws
__global__ void ode_prep(const float* __restrict__ W0, const float* __restrict__ W1,
                         const float* __restrict__ W2, const float* __restrict__ Wo,
                         const float* __restrict__ b0, const float* __restrict__ g0, const float* __restrict__ e0,
                         const float* __restrict__ b1, const float* __restrict__ g1, const float* __restrict__ e1,
                         const float* __restrict__ b2, const float* __restrict__ g2, const float* __restrict__ e2,
                         const float* __restrict__ bo, void* __restrict__ ws)
{
  const int f = blockIdx.x, l = threadIdx.x, lg = l>>4, lc = l&15;
  short* wsA = (short*)ws;
  float* wsP = (float*)((char*)ws + WSP_BYTES);
  if (f < 120){
    union { unsigned short u[8]; uint4 q; } r;
    if (f < 16){                       // A0Z: z-part of W0, zeta-permuted rows
      const int t = f>>1, kt = f&1;
#pragma unroll
      for (int j=0;j<8;++j){
        const int row = 16*(2*kt + (j>>2)) + 4*lg + (j&3);
        r.u[j] = f2bf(W0[(size_t)row*128 + 16*t + lc]);
      }
    } else if (f < 40){                // A0C: cond-part of W0, natural rows
      const int g = f-16, t = g/3, c = g - 3*t;
#pragma unroll
      for (int j=0;j<8;++j){
        const int row = 64 + c*32 + lg*8 + j;
        r.u[j] = f2bf(W0[(size_t)row*128 + 16*t + lc]);
      }
    } else if (f < 72){                // A1: pi-permuted
      const int g = f-40, t = g>>2, kt = g&3;
#pragma unroll
      for (int j=0;j<8;++j){
        const int row = 16*(2*kt + (j>>2)) + 4*lg + (j&3);
        r.u[j] = f2bf(W1[(size_t)row*128 + 16*t + lc]);
      }
    } else if (f < 104){               // A2
      const int g = f-72, t = g>>2, kt = g&3;
#pragma unroll
      for (int j=0;j<8;++j){
        const int row = 16*(2*kt + (j>>2)) + 4*lg + (j&3);
        r.u[j] = f2bf(W2[(size_t)row*128 + 16*t + lc]);
      }
    } else {                           // AO: Wo (ld 64), pi-permuted
      const int g = f-104, t = g>>2, kt = g&3;
#pragma unroll
      for (int j=0;j<8;++j){
        const int row = 16*(2*kt + (j>>2)) + 4*lg + (j&3);
        r.u[j] = f2bf(Wo[(size_t)row*64 + 16*t + lc]);
      }
    }
    *(uint4*)(wsA + (size_t)f*512 + l*8) = r.q;
  } else {
    for (int idx=l; idx<1216; idx+=64){
      const int a = idx>>7, rr = idx&127;
      float v;
      switch(a){
        case 0: v=b0[rr]; break; case 1: v=g0[rr]; break; case 2: v=e0[rr]; break;
        case 3: v=b1[rr]; break; case 4: v=g1[rr]; break; case 5: v=e1[rr]; break;
        case 6: v=b2[rr]; break; case 7: v=g2[rr]; break; case 8: v=e2[rr]; break;
        default: v=bo[idx-1152]; break;
      }
      wsP[idx]=v;
    }
  }
}

// LN + tanh + pack: acc (8 tiles x f4) -> B[4]; stats via 4 in-wave shuffles only
__device__ __forceinline__ void ln_pack(f4 (&acc)[8], const float* __restrict__ gp,
                                        const float* __restrict__ ep, bfrag (&B)[4]){
  float s=0.f, q=0.f;
#pragma unroll
  for (int t=0;t<8;++t){
    s += (acc[t][0]+acc[t][1]) + (acc[t][2]+acc[t][3]);
    q += fmaf(acc[t][0],acc[t][0], acc[t][1]*acc[t][1])
       + fmaf(acc[t][2],acc[t][2], acc[t][3]*acc[t][3]);
  }
  s += __shfl_xor(s,16); q += __shfl_xor(q,16);
  s += __shfl_xor(s,32); q += __shfl_xor(q,32);
  const float mu = s*0.0078125f;
  const float rs = rsqrtf(fmaf(q,0.0078125f,-mu*mu)+EPS);
#pragma unroll
  for (int t=0;t<8;++t){
    const f4 gg = *(const f4*)(gp + 16*t);
    const f4 bb = *(const f4*)(ep + 16*t);
#pragma unroll
    for (int g=0; g<4; ++g)
      acc[t][g] = tanh_fast(fmaf((acc[t][g]-mu)*rs, gg[g], bb[g]));
  }
  union { bfrag v; uint32_t u[4]; } r;
#pragma unroll
  for (int kt=0;kt<4;++kt){
    r.u[0]=pk2bf(acc[2*kt][0],  acc[2*kt][1]);
    r.u[1]=pk2bf(acc[2*kt][2],  acc[2*kt][3]);
    r.u[2]=pk2bf(acc[2*kt+1][0],acc[2*kt+1][1]);
    r.u[3]=pk2bf(acc[2*kt+1][2],acc[2*kt+1][3]);
    B[kt]=r.v;
  }
}

__device__ __forceinline__ void cvt_cond(const f4 (&cf)[6], bfrag (&Bc)[3]){
  union { bfrag v; uint32_t u[4]; } r;
#pragma unroll
  for (int c=0;c<3;++c){
    r.u[0]=pk2bf(cf[2*c][0],cf[2*c][1]);
    r.u[1]=pk2bf(cf[2*c][2],cf[2*c][3]);
    r.u[2]=pk2bf(cf[2*c+1][0],cf[2*c+1][1]);
    r.u[3]=pk2bf(cf[2*c+1][2],cf[2*c+1][3]);
    Bc[c]=r.v;
  }
}

__global__ __launch_bounds__(64,1)
void ode_step(const short* __restrict__ wf, const float* __restrict__ wp,
              const float* __restrict__ z0, const float* __restrict__ tt,
              const float* __restrict__ cond, float* __restrict__ out)
{
  extern __shared__ char lds_raw[];
  short* lfb = (short*)lds_raw;
  float* lpb = (float*)(lds_raw + L_FRAG_SHORTS*2);

  const int l = threadIdx.x, lg = l>>4, lc = l&15;
  const int r0 = blockIdx.x*16;

  // ---- one-time: copy A0C/A1/A2 frags (ws bytes 16K..104K) + params into LDS
  {
    const uint4* s1 = (const uint4*)((const char*)wf + 16*1024);
    uint4* d1 = (uint4*)lds_raw;
    for (int idx=l; idx<5632; idx+=64) d1[idx] = s1[idx];
    const uint4* s2 = (const uint4*)wp;
    uint4* d2 = (uint4*)(lds_raw + L_FRAG_SHORTS*2);
    for (int idx=l; idx<304; idx+=64) d2[idx] = s2[idx];
  }
  // ---- one-time: A0Z + AO fragments into registers
  bfrag A0zr[16], AOr[16];
  {
    const short* wg = wf + l*8;
#pragma unroll
    for (int n=0;n<16;++n) A0zr[n] = *(const bfrag*)(wg + F_A0Z + n*512);
#pragma unroll
    for (int n=0;n<16;++n) AOr[n]  = *(const bfrag*)(wg + F_AO + n*512);
  }
  asm volatile("s_waitcnt vmcnt(0) lgkmcnt(0)" ::: "memory");  // single wave: no barrier

  // time pipeline
  const float* tp = tt + (size_t)(r0+lc)*NSEQ;
  float tcv = tp[0], tnv = tp[1];

  // z in registers: zr[t][g] = z[batch lc][16t+4lg+g]; pack Bz; write out step 0
  f4 zr[4];
  bfrag Bz0, Bz1;
  {
    const float* zp = z0 + (size_t)(r0+lc)*64 + 4*lg;
    float* op = out + ((size_t)(r0+lc)*NSEQ)*64 + 4*lg;
#pragma unroll
    for (int t=0;t<4;++t){
      zr[t] = *(const f4*)(zp + 16*t);
      *(f4*)(op + 16*t) = zr[t];
    }
    union { bfrag v; uint32_t u[4]; } a, b;
    a.u[0]=pk2bf(zr[0][0],zr[0][1]); a.u[1]=pk2bf(zr[0][2],zr[0][3]);
    a.u[2]=pk2bf(zr[1][0],zr[1][1]); a.u[3]=pk2bf(zr[1][2],zr[1][3]);
    b.u[0]=pk2bf(zr[2][0],zr[2][1]); b.u[1]=pk2bf(zr[2][2],zr[2][3]);
    b.u[2]=pk2bf(zr[3][0],zr[3][1]); b.u[3]=pk2bf(zr[3][2],zr[3][3]);
    Bz0=a.v; Bz1=b.v;
  }

  // cond pointer for this lane
  const float* cb = cond + ((size_t)(r0+lc)*NSEQ)*96 + lg*8;
  f4 cf[6];
#pragma unroll
  for (int c=0;c<3;++c){
    cf[2*c]   = *(const f4*)(cb + c*32);
    cf[2*c+1] = *(const f4*)(cb + c*32 + 4);
  }

  // prologue: apC(0) = bias0 + cond(0) @ W0c
  f4 apC[8];
  {
    bfrag Bc[3];
    cvt_cond(cf, Bc);
    const short* lf0 = lfb + l*8;
    const float* lp0 = lpb + 4*lg;
#pragma unroll
    for (int t=0;t<8;++t) apC[t] = *(const f4*)(lp0 + P_B0 + 16*t);
#pragma unroll
    for (int c=0;c<3;++c)
#pragma unroll
      for (int t=0;t<8;++t){
        const bfrag a = *(const bfrag*)(lf0 + L_A0C + (t*3+c)*512);
        apC[t] = MFMA16(a, Bc[c], apC[t],0,0,0);
      }
  }
  // cf <- cond(1)
#pragma unroll
  for (int c=0;c<3;++c){
    cf[2*c]   = *(const f4*)(cb + 96 + c*32);
    cf[2*c+1] = *(const f4*)(cb + 96 + c*32 + 4);
  }

  int iz = 0;
  for (int i=0; i<NSEQ-1; ++i){
    asm("" : "+v"(iz));                       // defeat LICM / keep loads in-loop
    const short* lfi = lfb + l*8 + iz;
    const float* lpi = lpb + 4*lg + iz;

    // ---- L0: z MFMAs into apC (holds bias0 + cond(i))
#pragma unroll
    for (int t=0;t<8;++t)
      apC[t] = MFMA16(A0zr[t*2+0], Bz0, apC[t],0,0,0);
#pragma unroll
    for (int t=0;t<8;++t)
      apC[t] = MFMA16(A0zr[t*2+1], Bz1, apC[t],0,0,0);
    bfrag B[4];
    ln_pack(apC, lpi + P_G0, lpi + P_E0, B);

    // ---- L1
    f4 acc[8];
#pragma unroll
    for (int t=0;t<8;++t) acc[t] = *(const f4*)(lpi + P_B1 + 16*t);
#pragma unroll
    for (int kt=0;kt<4;++kt)
#pragma unroll
      for (int t=0;t<8;++t){
        const bfrag a = *(const bfrag*)(lfi + L_A1 + (t*4+kt)*512);
        acc[t] = MFMA16(a, B[kt], acc[t],0,0,0);
      }
    ln_pack(acc, lpi + P_G1, lpi + P_E1, B);

    // ---- rebuild apC for step i+1: bias0 + cond(i+1) @ W0c (overlaps LN phases)
    {
      bfrag Bc[3];
      cvt_cond(cf, Bc);
#pragma unroll
      for (int t=0;t<8;++t) apC[t] = *(const f4*)(lpi + P_B0 + 16*t);
#pragma unroll
      for (int c=0;c<3;++c)
#pragma unroll
        for (int t=0;t<8;++t){
          const bfrag a = *(const bfrag*)(lfi + L_A0C + (t*3+c)*512);
          apC[t] = MFMA16(a, Bc[c], apC[t],0,0,0);
        }
      const int ic = (i < NSEQ-2) ? (i+2) : (NSEQ-1);
      const float* cbi = cb + (size_t)ic*96;
#pragma unroll
      for (int c=0;c<3;++c){
        cf[2*c]   = *(const f4*)(cbi + c*32);
        cf[2*c+1] = *(const f4*)(cbi + c*32 + 4);
      }
    }

    // ---- L2
#pragma unroll
    for (int t=0;t<8;++t) acc[t] = *(const f4*)(lpi + P_B2 + 16*t);
#pragma unroll
    for (int kt=0;kt<4;++kt)
#pragma unroll
      for (int t=0;t<8;++t){
        const bfrag a = *(const bfrag*)(lfi + L_A2 + (t*4+kt)*512);
        acc[t] = MFMA16(a, B[kt], acc[t],0,0,0);
      }
    ln_pack(acc, lpi + P_G2, lpi + P_E2, B);

    // ---- Lo + Euler + store + z re-pack (AO in registers)
    {
      f4 ao[4];
#pragma unroll
      for (int t=0;t<4;++t) ao[t] = *(const f4*)(lpi + P_BO + 16*t);
#pragma unroll
      for (int kt=0;kt<4;++kt)
#pragma unroll
        for (int t=0;t<4;++t)
          ao[t] = MFMA16(AOr[t*4+kt], B[kt], ao[t],0,0,0);
      const int ip2 = (i < NSEQ-2) ? (i+2) : (NSEQ-1);
      const float tfv = tp[ip2];
      const float dt = tnv - tcv;
      float* op = out + ((size_t)(r0+lc)*NSEQ + (size_t)(i+1))*64 + 4*lg;
#pragma unroll
      for (int t=0;t<4;++t){
#pragma unroll
        for (int g=0;g<4;++g) zr[t][g] = fmaf(dt, ao[t][g], zr[t][g]);
        *(f4*)(op + 16*t) = zr[t];
      }
      union { bfrag v; uint32_t u[4]; } a, b;
      a.u[0]=pk2bf(zr[0][0],zr[0][1]); a.u[1]=pk2bf(zr[0][2],zr[0][3]);
      a.u[2]=pk2bf(zr[1][0],zr[1][1]); a.u[3]=pk2bf(zr[1][2],zr[1][3]);
      b.u[0]=pk2bf(zr[2][0],zr[2][1]); b.u[1]=pk2bf(zr[2][2],zr[2][3]);
      b.u[2]=pk2bf(zr[3][0],zr[3][1]); b.u[3]=pk2bf(zr[3][2],zr[3][3]);
      Bz0=a.v; Bz1=b.v;
      tcv = tnv; tnv = tfv;
    }
  }
}

extern "C" void kernel_launch(void* const* d_in, const int* in_sizes, int n_in,
                              void* d_out, int out_size, void* d_ws, size_t ws_size,
                              hipStream_t stream) {
  const float* z0   = (const float*)d_in[0];
  const float* tt   = (const float*)d_in[1];
  const float* cond = (const float*)d_in[2];
  const float* W0   = (const float*)d_in[3];
  const float* b0   = (const float*)d_in[4];
  const float* g0   = (const float*)d_in[5];
  const float* be0  = (const float*)d_in[6];
  const float* W1   = (const float*)d_in[7];
  const float* b1   = (const float*)d_in[8];
  const float* g1   = (const float*)d_in[9];
  const float* be1  = (const float*)d_in[10];
  const float* W2   = (const float*)d_in[11];
  const float* b2   = (const float*)d_in[12];
  const float* g2   = (const float*)d_in[13];
  const float* be2  = (const float*)d_in[14];
  const float* Wo   = (const float*)d_in[15];
  const float* bo   = (const float*)d_in[16];
  float* out = (float*)d_out;

  // opt-in to >64KB dynamic LDS (gfx950 has 160KB/CU)
  (void)hipFuncSetAttribute((const void*)ode_step,
                            hipFuncAttributeMaxDynamicSharedMemorySize,
                            L_TOTAL_BYTES);

  hipLaunchKernelGGL(ode_prep, dim3(121), dim3(64), 0, stream,
                     W0, W1, W2, Wo, b0, g0, be0, b1, g1, be1,
                     b2, g2, be2, bo, d_ws);
  hipLaunchKernelGGL(ode_step, dim3(64), dim3(64), L_TOTAL_BYTES, stream,
                     (const short*)d_ws, (const float*)((const char*)d_ws + WSP_BYTES),
                     z0, tt, cond, out);
}

// Round 13
// 1271.772 us; speedup vs baseline: 2.9275x; 1.8565x over previous
//
#include <hip/hip_runtime.h>
#include <stdint.h>

#define NSEQ 512
#define XS 104   // xin row stride (shorts): 96 cond + pad
#define AS 136   // act row stride (shorts)
#define PS 36    // part row stride (f32): 16 float2 slots + pad
#define LS 68    // lop row stride (f32): 64 latents + pad
#define EPS 1e-5f

typedef short bfrag __attribute__((ext_vector_type(8)));
typedef float f4 __attribute__((ext_vector_type(4)));
#define MFMA16 __builtin_amdgcn_mfma_f32_16x16x32_bf16

__device__ __forceinline__ unsigned short f2bf(float f){
  uint32_t u = __float_as_uint(f);
  u += 0x7FFFu + ((u>>16)&1u);   // RNE
  return (unsigned short)(u>>16);
}
__device__ __forceinline__ uint32_t pk2bf(float a, float b){
  uint32_t r;
  asm("v_cvt_pk_bf16_f32 %0, %1, %2" : "=v"(r) : "v"(a), "v"(b));
  return r;
}
__device__ __forceinline__ float tanh_fast(float v){
  float e = __builtin_amdgcn_exp2f(v * 2.8853900817779268f);  // e^(2v)
  float r = __builtin_amdgcn_rcpf(e + 1.f);
  return fmaf(-2.f, r, 1.f);
}
// LDS-only barrier: global loads/stores stay in flight across it
__device__ __forceinline__ void lds_barrier(){
  asm volatile("s_waitcnt lgkmcnt(0)" ::: "memory");
  __builtin_amdgcn_s_barrier();
  asm volatile("" ::: "memory");
}

// stats over lane's 8 neurons -> direct f2 write, 16 slots/row
__device__ __forceinline__ void stats_write(const float (&h0)[4], const float (&h1)[4],
                                            float* __restrict__ part,
                                            const int w, const int lg, const int lc){
  const float s = ((h0[0]+h0[1])+(h0[2]+h0[3])) + ((h1[0]+h1[1])+(h1[2]+h1[3]));
  const float q = (fmaf(h0[0],h0[0], h0[1]*h0[1]) + fmaf(h0[2],h0[2], h0[3]*h0[3]))
                + (fmaf(h1[0],h1[0], h1[1]*h1[1]) + fmaf(h1[2],h1[2], h1[3]*h1[3]));
  *(float2*)(part + lc*PS + (w*4+lg)*2) = make_float2(s, q);
}

__device__ __forceinline__ void ln_mu_rs(const float* __restrict__ part, const int lc,
                                         float& mu, float& rs){
  const float* pr = part + lc*PS;
  const f4 p0=*(const f4*)(pr),    p1=*(const f4*)(pr+4),  p2=*(const f4*)(pr+8),  p3=*(const f4*)(pr+12);
  const f4 p4=*(const f4*)(pr+16), p5=*(const f4*)(pr+20), p6=*(const f4*)(pr+24), p7=*(const f4*)(pr+28);
  const float ss = (((p0.x+p0.z)+(p1.x+p1.z)) + ((p2.x+p2.z)+(p3.x+p3.z)))
                 + (((p4.x+p4.z)+(p5.x+p5.z)) + ((p6.x+p6.z)+(p7.x+p7.z)));
  const float qq = (((p0.y+p0.w)+(p1.y+p1.w)) + ((p2.y+p2.w)+(p3.y+p3.w)))
                 + (((p4.y+p4.w)+(p5.y+p5.w)) + ((p6.y+p6.w)+(p7.y+p7.w)));
  mu = ss * 0.0078125f;
  rs = rsqrtf(fmaf(qq, 0.0078125f, -mu*mu) + EPS);
}

// LN + tanh + single-b128 act store (lane's 8 contiguous neurons)
__device__ __forceinline__ void ln_tanh_store(const float (&h0)[4], const float (&h1)[4],
    const float (&gd)[2][4], const float (&bed)[2][4],
    const float* __restrict__ part, unsigned short* __restrict__ actb,
    const int w, const int lg, const int lc){
  float mu, rs;
  ln_mu_rs(part, lc, mu, rs);
  float e0[4], e1[4];
#pragma unroll
  for (int g=0; g<4; ++g){
    e0[g] = tanh_fast(fmaf((h0[g]-mu)*rs, gd[0][g], bed[0][g]));
    e1[g] = tanh_fast(fmaf((h1[g]-mu)*rs, gd[1][g], bed[1][g]));
  }
  uint4 pk4;
  pk4.x = pk2bf(e0[0],e0[1]); pk4.y = pk2bf(e0[2],e0[3]);
  pk4.z = pk2bf(e1[0],e1[1]); pk4.w = pk2bf(e1[2],e1[3]);
  *(uint4*)(actb + lc*AS + w*32 + lg*8) = pk4;
}

// LN2 + tanh, but keep the result as this wave's own kt-slice B-frag (no LDS)
__device__ __forceinline__ bfrag ln_tanh_own(const float (&h0)[4], const float (&h1)[4],
    const float (&gd)[2][4], const float (&bed)[2][4],
    const float* __restrict__ part, const int lc){
  float mu, rs;
  ln_mu_rs(part, lc, mu, rs);
  float e0[4], e1[4];
#pragma unroll
  for (int g=0; g<4; ++g){
    e0[g] = tanh_fast(fmaf((h0[g]-mu)*rs, gd[0][g], bed[0][g]));
    e1[g] = tanh_fast(fmaf((h1[g]-mu)*rs, gd[1][g], bed[1][g]));
  }
  union { bfrag v; uint32_t u[4]; } r;
  r.u[0]=pk2bf(e0[0],e0[1]); r.u[1]=pk2bf(e0[2],e0[3]);
  r.u[2]=pk2bf(e1[0],e1[1]); r.u[3]=pk2bf(e1[2],e1[3]);
  return r.v;
}

__global__ __launch_bounds__(256, 1)
void latent_ode_v13(const float* __restrict__ z0, const float* __restrict__ tt,
                    const float* __restrict__ cond,
                    const float* __restrict__ W0, const float* __restrict__ b0,
                    const float* __restrict__ g0, const float* __restrict__ be0,
                    const float* __restrict__ W1, const float* __restrict__ b1,
                    const float* __restrict__ g1, const float* __restrict__ be1,
                    const float* __restrict__ W2, const float* __restrict__ b2,
                    const float* __restrict__ g2, const float* __restrict__ be2,
                    const float* __restrict__ Wo, const float* __restrict__ bo,
                    float* __restrict__ out)
{
  __shared__ __align__(16) unsigned short xin[16*XS];      // cond only
  __shared__ __align__(16) unsigned short act[16*AS];      // act0/act1 (alternating)
  __shared__ __align__(16) float part[16*PS];              // LN stats slots
  __shared__ __align__(16) float lop[4*16*LS];             // Lo partials [src_w][batch][latent]

  const int t  = threadIdx.x;     // 0..255, 4 waves
  const int w  = t >> 6;
  const int l  = t & 63;
  const int lg = l >> 4;
  const int lc = l & 15;
  const int r0 = blockIdx.x * 16;

  // ---- hidden-layer weight fragments (v9 verbatim: lane owns 8 contiguous neurons)
  bfrag A0z[2][2], A0c[2][3], A1f[2][4], A2f[2][4];
#pragma unroll
  for (int nt=0; nt<2; ++nt){
    const int col = w*32 + nt*4 + ((lc>>2)<<3) + (lc&3);
#pragma unroll
    for (int kt=0; kt<2; ++kt){
      union { bfrag v; unsigned short u[8]; } r;
#pragma unroll
      for (int j=0; j<8; ++j) r.u[j] = f2bf(W0[(size_t)(kt*32 + lg*8 + j)*128 + col]);
      A0z[nt][kt] = r.v;
    }
#pragma unroll
    for (int s=0; s<3; ++s){
      union { bfrag v; unsigned short u[8]; } r;
#pragma unroll
      for (int j=0; j<8; ++j) r.u[j] = f2bf(W0[(size_t)(64 + s*32 + lg*8 + j)*128 + col]);
      A0c[nt][s] = r.v;
    }
#pragma unroll
    for (int kt=0; kt<4; ++kt){
      union { bfrag v; unsigned short u[8]; } r1, r2;
#pragma unroll
      for (int j=0; j<8; ++j){
        const int k = kt*32 + lg*8 + j;
        r1.u[j] = f2bf(W1[(size_t)k*128 + col]);
        r2.u[j] = f2bf(W2[(size_t)k*128 + col]);
      }
      A1f[nt][kt] = r1.v; A2f[nt][kt] = r2.v;
    }
  }
  // ---- Lo fragments: own kt=w rows only, all 4 latent n-tiles
  bfrag Aof[4];
#pragma unroll
  for (int nt=0; nt<4; ++nt){
    union { bfrag v; unsigned short u[8]; } r;
#pragma unroll
    for (int j=0; j<8; ++j)
      r.u[j] = f2bf(Wo[(size_t)(w*32 + lg*8 + j)*64 + (nt*16 + lc)]);
    Aof[nt] = r.v;
  }
  float bd0[2][4], gd0[2][4], bed0[2][4];
  float bd1[2][4], gd1[2][4], bed1[2][4];
  float bd2[2][4], gd2[2][4], bed2[2][4];
#pragma unroll
  for (int nt=0; nt<2; ++nt){
#pragma unroll
    for (int g=0; g<4; ++g){
      const int n = w*32 + lg*8 + nt*4 + g;
      bd0[nt][g]=b0[n]; gd0[nt][g]=g0[n]; bed0[nt][g]=be0[n];
      bd1[nt][g]=b1[n]; gd1[nt][g]=g1[n]; bed1[nt][g]=be1[n];
      bd2[nt][g]=b2[n]; gd2[nt][g]=g2[n]; bed2[nt][g]=be2[n];
    }
  }
  // bo for this lane's 16 L0-latents: {8lg+j} and {32+8lg+j}
  f4 bo0a = *(const f4*)(bo + 8*lg);
  f4 bo0b = *(const f4*)(bo + 8*lg + 4);
  f4 bo1a = *(const f4*)(bo + 32 + 8*lg);
  f4 bo1b = *(const f4*)(bo + 32 + 8*lg + 4);

  // ---- t pipeline: at S_A(i): tcv=t[i-1], tnv=t[i]
  const float* tp = tt + (size_t)(r0+lc)*NSEQ;
  float tcv = 0.f, tnv = tp[0];

  // ---- z state: lane holds latents {8lg..8lg+8} and {32+8lg..+8} (redundant per wave)
  f4 za0, za1, zb0, zb1;   // za: first 8, zb: second 8
  bfrag Bz0, Bz1;
  {
    const float* zp = z0 + (size_t)(r0+lc)*64;
    za0 = *(const f4*)(zp + 8*lg);
    za1 = *(const f4*)(zp + 8*lg + 4);
    zb0 = *(const f4*)(zp + 32 + 8*lg);
    zb1 = *(const f4*)(zp + 32 + 8*lg + 4);
    if (w == 0){
      float* op = out + ((size_t)(r0+lc)*NSEQ)*64;
      *(f4*)(op + 8*lg) = za0;  *(f4*)(op + 8*lg + 4) = za1;
      *(f4*)(op + 32 + 8*lg) = zb0;  *(f4*)(op + 32 + 8*lg + 4) = zb1;
    }
    union { bfrag v; uint32_t u[4]; } a, b;
    a.u[0]=pk2bf(za0[0],za0[1]); a.u[1]=pk2bf(za0[2],za0[3]);
    a.u[2]=pk2bf(za1[0],za1[1]); a.u[3]=pk2bf(za1[2],za1[3]);
    b.u[0]=pk2bf(zb0[0],zb0[1]); b.u[1]=pk2bf(zb0[2],zb0[3]);
    b.u[2]=pk2bf(zb1[0],zb1[1]); b.u[3]=pk2bf(zb1[2],zb1[3]);
    Bz0=a.v; Bz1=b.v;
  }

  // ---- cond staging: 12 threads/row x 8 f32 -> one b128 bf16 write (v9 verbatim)
  const bool stgW = (t < 192);
  const int srow = t / 12, s8 = t - srow*12;
  const float* cptr = cond + ((size_t)(r0+srow)*NSEQ)*96 + s8*8;
  float4 pf0 = {0,0,0,0}, pf1 = {0,0,0,0};
  if (stgW){
    const float4 c0 = *(const float4*)(cptr);
    const float4 c1 = *(const float4*)(cptr + 4);
    uint4 u;
    u.x = pk2bf(c0.x,c0.y); u.y = pk2bf(c0.z,c0.w);
    u.z = pk2bf(c1.x,c1.y); u.w = pk2bf(c1.z,c1.w);
    *(uint4*)(xin + srow*XS + s8*8) = u;
    pf0 = *(const float4*)(cptr + 96);
    pf1 = *(const float4*)(cptr + 100);
  }
  lds_barrier();   // Bp1: cond(0) visible

  // ---- prologue preacc of cond(0)
  f4 apC[2];
  {
    const int o = lc*XS + lg*8;
    const bfrag c0 = *(const bfrag*)(xin + o);
    const bfrag c1 = *(const bfrag*)(xin + o + 32);
    const bfrag c2 = *(const bfrag*)(xin + o + 64);
    const f4 z4 = {0,0,0,0};
#pragma unroll
    for (int nt=0; nt<2; ++nt){
      f4 a = MFMA16(A0c[nt][0], c0, z4, 0,0,0);
      a = MFMA16(A0c[nt][1], c1, a, 0,0,0);
      a = MFMA16(A0c[nt][2], c2, a, 0,0,0);
      apC[nt] = a;
    }
  }
  lds_barrier();   // Bp2: protect cond(0) reads from step-0 staging overwrite

  float h0[4], h1[4];
  for (int i=0; i<NSEQ-1; ++i){
    // ---- S_A: [sum Lo partials -> Euler -> pack Bz] (i>0), L0 z MFMAs,
    //           stats, cond staging, t prefetch
    const float tfv = tp[i+1];
    if (i > 0){
      const float dt = tnv - tcv;
      // half A: latents 8lg..8lg+8
      {
        const float* lpA = lop + lc*LS + 8*lg;
        const f4 p0 = *(const f4*)(lpA);
        const f4 p1 = *(const f4*)(lpA + 16*LS);
        const f4 p2 = *(const f4*)(lpA + 32*LS);
        const f4 p3 = *(const f4*)(lpA + 48*LS);
        const f4 q0 = *(const f4*)(lpA + 4);
        const f4 q1 = *(const f4*)(lpA + 16*LS + 4);
        const f4 q2 = *(const f4*)(lpA + 32*LS + 4);
        const f4 q3 = *(const f4*)(lpA + 48*LS + 4);
        const f4 dza = (((p0+p1)+p2)+p3) + bo0a;
        const f4 dzb = (((q0+q1)+q2)+q3) + bo0b;
#pragma unroll
        for (int g=0; g<4; ++g){
          za0[g] = fmaf(dt, dza[g], za0[g]);
          za1[g] = fmaf(dt, dzb[g], za1[g]);
        }
      }
      // half B: latents 32+8lg..+8
      {
        const float* lpB = lop + lc*LS + 32 + 8*lg;
        const f4 p0 = *(const f4*)(lpB);
        const f4 p1 = *(const f4*)(lpB + 16*LS);
        const f4 p2 = *(const f4*)(lpB + 32*LS);
        const f4 p3 = *(const f4*)(lpB + 48*LS);
        const f4 q0 = *(const f4*)(lpB + 4);
        const f4 q1 = *(const f4*)(lpB + 16*LS + 4);
        const f4 q2 = *(const f4*)(lpB + 32*LS + 4);
        const f4 q3 = *(const f4*)(lpB + 48*LS + 4);
        const f4 dza = (((p0+p1)+p2)+p3) + bo1a;
        const f4 dzb = (((q0+q1)+q2)+q3) + bo1b;
#pragma unroll
        for (int g=0; g<4; ++g){
          zb0[g] = fmaf(dt, dza[g], zb0[g]);
          zb1[g] = fmaf(dt, dzb[g], zb1[g]);
        }
      }
      if (w == 0){
        float* op = out + ((size_t)(r0+lc)*NSEQ + (size_t)i)*64;
        *(f4*)(op + 8*lg) = za0;  *(f4*)(op + 8*lg + 4) = za1;
        *(f4*)(op + 32 + 8*lg) = zb0;  *(f4*)(op + 32 + 8*lg + 4) = zb1;
      }
      union { bfrag v; uint32_t u[4]; } a, b;
      a.u[0]=pk2bf(za0[0],za0[1]); a.u[1]=pk2bf(za0[2],za0[3]);
      a.u[2]=pk2bf(za1[0],za1[1]); a.u[3]=pk2bf(za1[2],za1[3]);
      b.u[0]=pk2bf(zb0[0],zb0[1]); b.u[1]=pk2bf(zb0[2],zb0[3]);
      b.u[2]=pk2bf(zb1[0],zb1[1]); b.u[3]=pk2bf(zb1[2],zb1[3]);
      Bz0=a.v; Bz1=b.v;
    }
    // L0 z-part (v9 verbatim, Bz from regs)
    {
      const f4 z4 = {0,0,0,0};
      f4 c0 = MFMA16(A0z[0][0], Bz0, z4, 0,0,0);
      f4 c1 = MFMA16(A0z[1][0], Bz0, z4, 0,0,0);
      c0 = MFMA16(A0z[0][1], Bz1, c0, 0,0,0);
      c1 = MFMA16(A0z[1][1], Bz1, c1, 0,0,0);
#pragma unroll
      for (int g=0; g<4; ++g){
        h0[g] = (c0[g] + apC[0][g]) + bd0[0][g];
        h1[g] = (c1[g] + apC[1][g]) + bd0[1][g];
      }
      stats_write(h0, h1, part, w, lg, lc);
    }
    if (stgW){
      uint4 u;
      u.x = pk2bf(pf0.x,pf0.y); u.y = pk2bf(pf0.z,pf0.w);
      u.z = pk2bf(pf1.x,pf1.y); u.w = pk2bf(pf1.z,pf1.w);
      *(uint4*)(xin + srow*XS + s8*8) = u;
      if (i < NSEQ-2){
        pf0 = *(const float4*)(cptr + (size_t)(i+2)*96);
        pf1 = *(const float4*)(cptr + (size_t)(i+2)*96 + 4);
      }
    }
    tcv = tnv; tnv = tfv;
    lds_barrier();   // B1

    // ---- S_B: LN0 + preacc cond(i+1)
    {
      const int o = lc*XS + lg*8;
      const bfrag c0 = *(const bfrag*)(xin + o);
      const bfrag c1 = *(const bfrag*)(xin + o + 32);
      const bfrag c2 = *(const bfrag*)(xin + o + 64);
      const f4 z4 = {0,0,0,0};
      f4 a0 = MFMA16(A0c[0][0], c0, z4, 0,0,0);
      f4 a1 = MFMA16(A0c[1][0], c0, z4, 0,0,0);
      a0 = MFMA16(A0c[0][1], c1, a0, 0,0,0);
      a1 = MFMA16(A0c[1][1], c1, a1, 0,0,0);
      a0 = MFMA16(A0c[0][2], c2, a0, 0,0,0);
      a1 = MFMA16(A0c[1][2], c2, a1, 0,0,0);
      ln_tanh_store(h0, h1, gd0, bed0, part, act, w, lg, lc);
      apC[0] = a0; apC[1] = a1;
    }
    lds_barrier();   // B2

    // ---- S_C: L1 + stats
    {
      const int o = lc*AS + lg*8;
      const bfrag b0f = *(const bfrag*)(act + o);
      const bfrag b1f = *(const bfrag*)(act + o + 32);
      const bfrag b2f = *(const bfrag*)(act + o + 64);
      const bfrag b3f = *(const bfrag*)(act + o + 96);
      const f4 z4 = {0,0,0,0};
      f4 ca0 = MFMA16(A1f[0][0], b0f, z4, 0,0,0);
      f4 cb0 = MFMA16(A1f[0][1], b1f, z4, 0,0,0);
      f4 ca1 = MFMA16(A1f[1][0], b0f, z4, 0,0,0);
      f4 cb1 = MFMA16(A1f[1][1], b1f, z4, 0,0,0);
      ca0 = MFMA16(A1f[0][2], b2f, ca0, 0,0,0);
      cb0 = MFMA16(A1f[0][3], b3f, cb0, 0,0,0);
      ca1 = MFMA16(A1f[1][2], b2f, ca1, 0,0,0);
      cb1 = MFMA16(A1f[1][3], b3f, cb1, 0,0,0);
#pragma unroll
      for (int g=0; g<4; ++g){
        h0[g] = (ca0[g]+cb0[g]) + bd1[0][g];
        h1[g] = (ca1[g]+cb1[g]) + bd1[1][g];
      }
      stats_write(h0, h1, part, w, lg, lc);
    }
    lds_barrier();   // B3

    // ---- S_D: LN1
    ln_tanh_store(h0, h1, gd1, bed1, part, act, w, lg, lc);
    lds_barrier();   // B4

    // ---- S_E: L2 + stats
    {
      const int o = lc*AS + lg*8;
      const bfrag b0f = *(const bfrag*)(act + o);
      const bfrag b1f = *(const bfrag*)(act + o + 32);
      const bfrag b2f = *(const bfrag*)(act + o + 64);
      const bfrag b3f = *(const bfrag*)(act + o + 96);
      const f4 z4 = {0,0,0,0};
      f4 ca0 = MFMA16(A2f[0][0], b0f, z4, 0,0,0);
      f4 cb0 = MFMA16(A2f[0][1], b1f, z4, 0,0,0);
      f4 ca1 = MFMA16(A2f[1][0], b0f, z4, 0,0,0);
      f4 cb1 = MFMA16(A2f[1][1], b1f, z4, 0,0,0);
      ca0 = MFMA16(A2f[0][2], b2f, ca0, 0,0,0);
      cb0 = MFMA16(A2f[0][3], b3f, cb0, 0,0,0);
      ca1 = MFMA16(A2f[1][2], b2f, ca1, 0,0,0);
      cb1 = MFMA16(A2f[1][3], b3f, cb1, 0,0,0);
#pragma unroll
      for (int g=0; g<4; ++g){
        h0[g] = (ca0[g]+cb0[g]) + bd2[0][g];
        h1[g] = (ca1[g]+cb1[g]) + bd2[1][g];
      }
      stats_write(h0, h1, part, w, lg, lc);
    }
    lds_barrier();   // B5

    // ---- S_F: LN2 in-register + Lo partials (own kt=w) + write
    {
      const bfrag Bown = ln_tanh_own(h0, h1, gd2, bed2, part, lc);
      const f4 z4 = {0,0,0,0};
      f4 lp0 = MFMA16(Aof[0], Bown, z4, 0,0,0);
      f4 lp1 = MFMA16(Aof[1], Bown, z4, 0,0,0);
      f4 lp2 = MFMA16(Aof[2], Bown, z4, 0,0,0);
      f4 lp3 = MFMA16(Aof[3], Bown, z4, 0,0,0);
      float* lw = lop + (size_t)w*16*LS + lc*LS + lg*4;
      *(f4*)(lw)      = lp0;
      *(f4*)(lw + 16) = lp1;
      *(f4*)(lw + 32) = lp2;
      *(f4*)(lw + 48) = lp3;
    }
    lds_barrier();   // B6
  }

  // ---- drain: final Euler for step NSEQ-1 (partials of dz_{510} in lop)
  {
    const float dt = tnv - tcv;
    if (w == 0){
      const float* lpA = lop + lc*LS + 8*lg;
      const f4 p0 = *(const f4*)(lpA);
      const f4 p1 = *(const f4*)(lpA + 16*LS);
      const f4 p2 = *(const f4*)(lpA + 32*LS);
      const f4 p3 = *(const f4*)(lpA + 48*LS);
      const f4 q0 = *(const f4*)(lpA + 4);
      const f4 q1 = *(const f4*)(lpA + 16*LS + 4);
      const f4 q2 = *(const f4*)(lpA + 32*LS + 4);
      const f4 q3 = *(const f4*)(lpA + 48*LS + 4);
      const f4 dza = (((p0+p1)+p2)+p3) + bo0a;
      const f4 dzb = (((q0+q1)+q2)+q3) + bo0b;
      const float* lpB = lop + lc*LS + 32 + 8*lg;
      const f4 r0v = *(const f4*)(lpB);
      const f4 r1v = *(const f4*)(lpB + 16*LS);
      const f4 r2v = *(const f4*)(lpB + 32*LS);
      const f4 r3v = *(const f4*)(lpB + 48*LS);
      const f4 s0v = *(const f4*)(lpB + 4);
      const f4 s1v = *(const f4*)(lpB + 16*LS + 4);
      const f4 s2v = *(const f4*)(lpB + 32*LS + 4);
      const f4 s3v = *(const f4*)(lpB + 48*LS + 4);
      const f4 dzc = (((r0v+r1v)+r2v)+r3v) + bo1a;
      const f4 dzd = (((s0v+s1v)+s2v)+s3v) + bo1b;
#pragma unroll
      for (int g=0; g<4; ++g){
        za0[g] = fmaf(dt, dza[g], za0[g]);
        za1[g] = fmaf(dt, dzb[g], za1[g]);
        zb0[g] = fmaf(dt, dzc[g], zb0[g]);
        zb1[g] = fmaf(dt, dzd[g], zb1[g]);
      }
      float* op = out + ((size_t)(r0+lc)*NSEQ + (size_t)(NSEQ-1))*64;
      *(f4*)(op + 8*lg) = za0;  *(f4*)(op + 8*lg + 4) = za1;
      *(f4*)(op + 32 + 8*lg) = zb0;  *(f4*)(op + 32 + 8*lg + 4) = zb1;
    }
  }
}

extern "C" void kernel_launch(void* const* d_in, const int* in_sizes, int n_in,
                              void* d_out, int out_size, void* d_ws, size_t ws_size,
                              hipStream_t stream) {
  const float* z0   = (const float*)d_in[0];
  const float* tt   = (const float*)d_in[1];
  const float* cond = (const float*)d_in[2];
  const float* W0   = (const float*)d_in[3];
  const float* b0   = (const float*)d_in[4];
  const float* g0   = (const float*)d_in[5];
  const float* be0  = (const float*)d_in[6];
  const float* W1   = (const float*)d_in[7];
  const float* b1   = (const float*)d_in[8];
  const float* g1   = (const float*)d_in[9];
  const float* be1  = (const float*)d_in[10];
  const float* W2   = (const float*)d_in[11];
  const float* b2   = (const float*)d_in[12];
  const float* g2   = (const float*)d_in[13];
  const float* be2  = (const float*)d_in[14];
  const float* Wo   = (const float*)d_in[15];
  const float* bo   = (const float*)d_in[16];
  float* out = (float*)d_out;

  hipLaunchKernelGGL(latent_ode_v13, dim3(64), dim3(256), 0, stream,
                     z0, tt, cond, W0, b0, g0, be0, W1, b1, g1, be1,
                     W2, b2, g2, be2, Wo, bo, out);
}

// Round 14
// 1133.993 us; speedup vs baseline: 3.2832x; 1.1215x over previous
//
#include <hip/hip_runtime.h>
#include <stdint.h>

#define NSEQ 512
#define XS 104   // xin row stride (shorts): 96 cond + pad
#define AS 136   // act row stride (shorts)
#define PS 36    // part row stride (f32): 16 float2 slots + pad
#define EPS 1e-5f

typedef short bfrag __attribute__((ext_vector_type(8)));
typedef float f4 __attribute__((ext_vector_type(4)));
#define MFMA16 __builtin_amdgcn_mfma_f32_16x16x32_bf16

__device__ __forceinline__ unsigned short f2bf(float f){
  uint32_t u = __float_as_uint(f);
  u += 0x7FFFu + ((u>>16)&1u);   // RNE
  return (unsigned short)(u>>16);
}
__device__ __forceinline__ uint32_t pk2bf(float a, float b){
  uint32_t r;
  asm("v_cvt_pk_bf16_f32 %0, %1, %2" : "=v"(r) : "v"(a), "v"(b));
  return r;
}
__device__ __forceinline__ float tanh_fast(float v){
  float e = __builtin_amdgcn_exp2f(v * 2.8853900817779268f);  // e^(2v)
  float r = __builtin_amdgcn_rcpf(e + 1.f);
  return fmaf(-2.f, r, 1.f);
}
// LDS-only barrier: global loads/stores stay in flight across it
__device__ __forceinline__ void lds_barrier(){
  asm volatile("s_waitcnt lgkmcnt(0)" ::: "memory");
  __builtin_amdgcn_s_barrier();
  asm volatile("" ::: "memory");
}

// stats over lane's 8 neurons -> direct f2 write, 16 slots/row (no shuffles)
__device__ __forceinline__ void stats_write(const float (&h0)[4], const float (&h1)[4],
                                            float* __restrict__ part,
                                            const int w, const int lg, const int lc){
  const float s = ((h0[0]+h0[1])+(h0[2]+h0[3])) + ((h1[0]+h1[1])+(h1[2]+h1[3]));
  const float q = (fmaf(h0[0],h0[0], h0[1]*h0[1]) + fmaf(h0[2],h0[2], h0[3]*h0[3]))
                + (fmaf(h1[0],h1[0], h1[1]*h1[1]) + fmaf(h1[2],h1[2], h1[3]*h1[3]));
  *(float2*)(part + lc*PS + (w*4+lg)*2) = make_float2(s, q);
}

// LN + tanh + single-b128 act store (lane's 8 contiguous neurons w*32+lg*8+0..7)
__device__ __forceinline__ void ln_tanh_store(const float (&h0)[4], const float (&h1)[4],
    const float (&gd)[2][4], const float (&bed)[2][4],
    const float* __restrict__ part, unsigned short* __restrict__ actb,
    const int w, const int lg, const int lc){
  const float* pr = part + lc*PS;
  const f4 p0=*(const f4*)(pr),    p1=*(const f4*)(pr+4),  p2=*(const f4*)(pr+8),  p3=*(const f4*)(pr+12);
  const f4 p4=*(const f4*)(pr+16), p5=*(const f4*)(pr+20), p6=*(const f4*)(pr+24), p7=*(const f4*)(pr+28);
  const float ss = (((p0.x+p0.z)+(p1.x+p1.z)) + ((p2.x+p2.z)+(p3.x+p3.z)))
                 + (((p4.x+p4.z)+(p5.x+p5.z)) + ((p6.x+p6.z)+(p7.x+p7.z)));
  const float qq = (((p0.y+p0.w)+(p1.y+p1.w)) + ((p2.y+p2.w)+(p3.y+p3.w)))
                 + (((p4.y+p4.w)+(p5.y+p5.w)) + ((p6.y+p6.w)+(p7.y+p7.w)));
  const float mu = ss * 0.0078125f;
  const float rs = rsqrtf(fmaf(qq, 0.0078125f, -mu*mu) + EPS);
  float e0[4], e1[4];
#pragma unroll
  for (int g=0; g<4; ++g){
    e0[g] = tanh_fast(fmaf((h0[g]-mu)*rs, gd[0][g], bed[0][g]));
    e1[g] = tanh_fast(fmaf((h1[g]-mu)*rs, gd[1][g], bed[1][g]));
  }
  uint4 pk4;
  pk4.x = pk2bf(e0[0],e0[1]); pk4.y = pk2bf(e0[2],e0[3]);
  pk4.z = pk2bf(e1[0],e1[1]); pk4.w = pk2bf(e1[2],e1[3]);
  *(uint4*)(actb + lc*AS + w*32 + lg*8) = pk4;
}

__global__ __launch_bounds__(256, 1)
void latent_ode_v14(const float* __restrict__ z0, const float* __restrict__ tt,
                    const float* __restrict__ cond,
                    const float* __restrict__ W0, const float* __restrict__ b0,
                    const float* __restrict__ g0, const float* __restrict__ be0,
                    const float* __restrict__ W1, const float* __restrict__ b1,
                    const float* __restrict__ g1, const float* __restrict__ be1,
                    const float* __restrict__ W2, const float* __restrict__ b2,
                    const float* __restrict__ g2, const float* __restrict__ be2,
                    const float* __restrict__ Wo, const float* __restrict__ bo,
                    float* __restrict__ out)
{
  __shared__ __align__(16) unsigned short xin[16*XS];   // cond only... [0:64 z][64:160 c]? no: see below
  __shared__ __align__(16) unsigned short act[16*AS];
  __shared__ __align__(16) float part[16*PS];
  // NOTE: v14 keeps v9's layout: xin row = [0:64 z][64:160 cond] with XS=168
  // -- but XS macro above is 104; we need the v9 XS. Redefine locally:
  // (kept as in v9 via XS2 below)
  static_assert(XS == 104, "");
  __shared__ __align__(16) unsigned short xinz[16*64];  // z region, stride 64

  const int t  = threadIdx.x;     // 0..255, 4 waves
  const int w  = t >> 6;
  const int l  = t & 63;
  const int lg = l >> 4;
  const int lc = l & 15;
  const int r0 = blockIdx.x * 16;
  const int zcol = w*16 + lg*4;

  // ---- weight fragments (v9 verbatim: lane owns 8 contiguous neurons)
  bfrag A0z[2][2], A0c[2][3], A1f[2][4], A2f[2][4], Aof[4];
#pragma unroll
  for (int nt=0; nt<2; ++nt){
    const int col = w*32 + nt*4 + ((lc>>2)<<3) + (lc&3);
#pragma unroll
    for (int kt=0; kt<2; ++kt){
      union { bfrag v; unsigned short u[8]; } r;
#pragma unroll
      for (int j=0; j<8; ++j) r.u[j] = f2bf(W0[(size_t)(kt*32 + lg*8 + j)*128 + col]);
      A0z[nt][kt] = r.v;
    }
#pragma unroll
    for (int s=0; s<3; ++s){
      union { bfrag v; unsigned short u[8]; } r;
#pragma unroll
      for (int j=0; j<8; ++j) r.u[j] = f2bf(W0[(size_t)(64 + s*32 + lg*8 + j)*128 + col]);
      A0c[nt][s] = r.v;
    }
#pragma unroll
    for (int kt=0; kt<4; ++kt){
      union { bfrag v; unsigned short u[8]; } r1, r2;
#pragma unroll
      for (int j=0; j<8; ++j){
        const int k = kt*32 + lg*8 + j;
        r1.u[j] = f2bf(W1[(size_t)k*128 + col]);
        r2.u[j] = f2bf(W2[(size_t)k*128 + col]);
      }
      A1f[nt][kt] = r1.v; A2f[nt][kt] = r2.v;
    }
  }
#pragma unroll
  for (int kt=0; kt<4; ++kt){
    union { bfrag v; unsigned short u[8]; } r;
#pragma unroll
    for (int j=0; j<8; ++j)
      r.u[j] = f2bf(Wo[(size_t)(kt*32 + lg*8 + j)*64 + (w*16 + lc)]);
    Aof[kt] = r.v;
  }
  float bd0[2][4], gd0[2][4], bed0[2][4];
  float bd1[2][4], gd1[2][4], bed1[2][4];
  float bd2[2][4], gd2[2][4], bed2[2][4];
  float bo_d[4];
#pragma unroll
  for (int nt=0; nt<2; ++nt){
#pragma unroll
    for (int g=0; g<4; ++g){
      const int n = w*32 + lg*8 + nt*4 + g;
      bd0[nt][g]=b0[n]; gd0[nt][g]=g0[n]; bed0[nt][g]=be0[n];
      bd1[nt][g]=b1[n]; gd1[nt][g]=g1[n]; bed1[nt][g]=be1[n];
      bd2[nt][g]=b2[n]; gd2[nt][g]=g2[n]; bed2[nt][g]=be2[n];
    }
  }
#pragma unroll
  for (int g=0; g<4; ++g) bo_d[g] = bo[zcol + g];

  // ---- t pipeline (registers, one prefetch per step)
  const float* tp = tt + (size_t)(r0+lc)*NSEQ;
  float tcv = tp[0], tnv = tp[1];

  // ---- z init
  f4 zr;
  {
    const f4 zv = *(const f4*)(z0 + (size_t)(r0+lc)*64 + zcol);
    zr = zv;
    *(uint2*)(xinz + lc*64 + zcol) = make_uint2(pk2bf(zv[0],zv[1]), pk2bf(zv[2],zv[3]));
    *(f4*)(out + ((size_t)(r0+lc)*NSEQ)*64 + zcol) = zv;
  }

  // ---- cond staging: 16 threads/row x 6 f32 each (balanced over all 4 waves)
  const int srow = t >> 4, sq = t & 15;
  const float* cptr = cond + ((size_t)(r0+srow)*NSEQ)*96 + sq*6;
  float2 pfa, pfb, pfc;
  {
    const float2 c0 = *(const float2*)(cptr);
    const float2 c1 = *(const float2*)(cptr + 2);
    const float2 c2 = *(const float2*)(cptr + 4);
    *(uint32_t*)(xin + srow*XS + sq*6)     = pk2bf(c0.x, c0.y);
    *(uint32_t*)(xin + srow*XS + sq*6 + 2) = pk2bf(c1.x, c1.y);
    *(uint32_t*)(xin + srow*XS + sq*6 + 4) = pk2bf(c2.x, c2.y);
    pfa = *(const float2*)(cptr + 96);
    pfb = *(const float2*)(cptr + 98);
    pfc = *(const float2*)(cptr + 100);
  }
  lds_barrier();

  // ---- prologue preacc of cond(0)
  f4 apC[2];
  {
    const int o = lc*XS + lg*8;
    const bfrag c0 = *(const bfrag*)(xin + o);
    const bfrag c1 = *(const bfrag*)(xin + o + 32);
    const bfrag c2 = *(const bfrag*)(xin + o + 64);
    const f4 z4 = {0,0,0,0};
#pragma unroll
    for (int nt=0; nt<2; ++nt){
      f4 a = MFMA16(A0c[nt][0], c0, z4, 0,0,0);
      a = MFMA16(A0c[nt][1], c1, a, 0,0,0);
      a = MFMA16(A0c[nt][2], c2, a, 0,0,0);
      apC[nt] = a;
    }
  }
  lds_barrier();   // protect cond(0) reads from step-0 staging overwrite

  float h0[4], h1[4];
  for (int i=0; i<NSEQ-1; ++i){
    // ---- S_A: L0 z-part + combine preacc; stats; stage cond(i+1); t prefetch
    const int ip2 = (i+2 <= NSEQ-1) ? (i+2) : (NSEQ-1);
    const float tfv = tp[ip2];
    {
      const int o = lc*64 + lg*8;
      const bfrag bz0 = *(const bfrag*)(xinz + o);
      const bfrag bz1 = *(const bfrag*)(xinz + o + 32);
      const f4 z4 = {0,0,0,0};
      f4 c0 = MFMA16(A0z[0][0], bz0, z4, 0,0,0);
      f4 c1 = MFMA16(A0z[1][0], bz0, z4, 0,0,0);
      c0 = MFMA16(A0z[0][1], bz1, c0, 0,0,0);
      c1 = MFMA16(A0z[1][1], bz1, c1, 0,0,0);
#pragma unroll
      for (int g=0; g<4; ++g){
        h0[g] = (c0[g] + apC[0][g]) + bd0[0][g];
        h1[g] = (c1[g] + apC[1][g]) + bd0[1][g];
      }
      stats_write(h0, h1, part, w, lg, lc);
    }
    {
      *(uint32_t*)(xin + srow*XS + sq*6)     = pk2bf(pfa.x, pfa.y);
      *(uint32_t*)(xin + srow*XS + sq*6 + 2) = pk2bf(pfb.x, pfb.y);
      *(uint32_t*)(xin + srow*XS + sq*6 + 4) = pk2bf(pfc.x, pfc.y);
      if (i < NSEQ-2){
        const float* cp2 = cptr + (size_t)(i+2)*96;
        pfa = *(const float2*)(cp2);
        pfb = *(const float2*)(cp2 + 2);
        pfc = *(const float2*)(cp2 + 4);
      }
    }
    lds_barrier();

    // ---- S_B: LN0 + preacc cond(i+1)
    {
      const int o = lc*XS + lg*8;
      const bfrag c0 = *(const bfrag*)(xin + o);
      const bfrag c1 = *(const bfrag*)(xin + o + 32);
      const bfrag c2 = *(const bfrag*)(xin + o + 64);
      const f4 z4 = {0,0,0,0};
      f4 a0 = MFMA16(A0c[0][0], c0, z4, 0,0,0);
      f4 a1 = MFMA16(A0c[1][0], c0, z4, 0,0,0);
      a0 = MFMA16(A0c[0][1], c1, a0, 0,0,0);
      a1 = MFMA16(A0c[1][1], c1, a1, 0,0,0);
      a0 = MFMA16(A0c[0][2], c2, a0, 0,0,0);
      a1 = MFMA16(A0c[1][2], c2, a1, 0,0,0);
      ln_tanh_store(h0, h1, gd0, bed0, part, act, w, lg, lc);
      apC[0] = a0; apC[1] = a1;
    }
    lds_barrier();

    // ---- S_C: L1
    {
      const int o = lc*AS + lg*8;
      const bfrag b0f = *(const bfrag*)(act + o);
      const bfrag b1f = *(const bfrag*)(act + o + 32);
      const bfrag b2f = *(const bfrag*)(act + o + 64);
      const bfrag b3f = *(const bfrag*)(act + o + 96);
      const f4 z4 = {0,0,0,0};
      f4 ca0 = MFMA16(A1f[0][0], b0f, z4, 0,0,0);
      f4 cb0 = MFMA16(A1f[0][1], b1f, z4, 0,0,0);
      f4 ca1 = MFMA16(A1f[1][0], b0f, z4, 0,0,0);
      f4 cb1 = MFMA16(A1f[1][1], b1f, z4, 0,0,0);
      ca0 = MFMA16(A1f[0][2], b2f, ca0, 0,0,0);
      cb0 = MFMA16(A1f[0][3], b3f, cb0, 0,0,0);
      ca1 = MFMA16(A1f[1][2], b2f, ca1, 0,0,0);
      cb1 = MFMA16(A1f[1][3], b3f, cb1, 0,0,0);
#pragma unroll
      for (int g=0; g<4; ++g){
        h0[g] = (ca0[g]+cb0[g]) + bd1[0][g];
        h1[g] = (ca1[g]+cb1[g]) + bd1[1][g];
      }
      stats_write(h0, h1, part, w, lg, lc);
    }
    lds_barrier();

    // ---- S_D: LN1
    ln_tanh_store(h0, h1, gd1, bed1, part, act, w, lg, lc);
    lds_barrier();

    // ---- S_E: L2
    {
      const int o = lc*AS + lg*8;
      const bfrag b0f = *(const bfrag*)(act + o);
      const bfrag b1f = *(const bfrag*)(act + o + 32);
      const bfrag b2f = *(const bfrag*)(act + o + 64);
      const bfrag b3f = *(const bfrag*)(act + o + 96);
      const f4 z4 = {0,0,0,0};
      f4 ca0 = MFMA16(A2f[0][0], b0f, z4, 0,0,0);
      f4 cb0 = MFMA16(A2f[0][1], b1f, z4, 0,0,0);
      f4 ca1 = MFMA16(A2f[1][0], b0f, z4, 0,0,0);
      f4 cb1 = MFMA16(A2f[1][1], b1f, z4, 0,0,0);
      ca0 = MFMA16(A2f[0][2], b2f, ca0, 0,0,0);
      cb0 = MFMA16(A2f[0][3], b3f, cb0, 0,0,0);
      ca1 = MFMA16(A2f[1][2], b2f, ca1, 0,0,0);
      cb1 = MFMA16(A2f[1][3], b3f, cb1, 0,0,0);
#pragma unroll
      for (int g=0; g<4; ++g){
        h0[g] = (ca0[g]+cb0[g]) + bd2[0][g];
        h1[g] = (ca1[g]+cb1[g]) + bd2[1][g];
      }
      stats_write(h0, h1, part, w, lg, lc);
    }
    lds_barrier();

    // ---- S_F: LN2
    ln_tanh_store(h0, h1, gd2, bed2, part, act, w, lg, lc);
    lds_barrier();

    // ---- S_G: Lo + Euler + stores (LDS z-write first, global store after)
    {
      const int o = lc*AS + lg*8;
      const bfrag b0f = *(const bfrag*)(act + o);
      const bfrag b1f = *(const bfrag*)(act + o + 32);
      const bfrag b2f = *(const bfrag*)(act + o + 64);
      const bfrag b3f = *(const bfrag*)(act + o + 96);
      const f4 z4 = {0,0,0,0};
      f4 aa = MFMA16(Aof[0], b0f, z4, 0,0,0);
      f4 ab = MFMA16(Aof[1], b1f, z4, 0,0,0);
      aa = MFMA16(Aof[2], b2f, aa, 0,0,0);
      ab = MFMA16(Aof[3], b3f, ab, 0,0,0);
      const float dt = tnv - tcv;
      f4 zn;
#pragma unroll
      for (int g=0; g<4; ++g) zn[g] = fmaf(dt, (aa[g]+ab[g]) + bo_d[g], zr[g]);
      zr = zn;
      *(uint2*)(xinz + lc*64 + zcol) = make_uint2(pk2bf(zn[0],zn[1]), pk2bf(zn[2],zn[3]));
      *(f4*)(out + ((size_t)(r0+lc)*NSEQ + (size_t)(i+1))*64 + zcol) = zn;
      tcv = tnv; tnv = tfv;
    }
    lds_barrier();
  }
}

extern "C" void kernel_launch(void* const* d_in, const int* in_sizes, int n_in,
                              void* d_out, int out_size, void* d_ws, size_t ws_size,
                              hipStream_t stream) {
  const float* z0   = (const float*)d_in[0];
  const float* tt   = (const float*)d_in[1];
  const float* cond = (const float*)d_in[2];
  const float* W0   = (const float*)d_in[3];
  const float* b0   = (const float*)d_in[4];
  const float* g0   = (const float*)d_in[5];
  const float* be0  = (const float*)d_in[6];
  const float* W1   = (const float*)d_in[7];
  const float* b1   = (const float*)d_in[8];
  const float* g1   = (const float*)d_in[9];
  const float* be1  = (const float*)d_in[10];
  const float* W2   = (const float*)d_in[11];
  const float* b2   = (const float*)d_in[12];
  const float* g2   = (const float*)d_in[13];
  const float* be2  = (const float*)d_in[14];
  const float* Wo   = (const float*)d_in[15];
  const float* bo   = (const float*)d_in[16];
  float* out = (float*)d_out;

  hipLaunchKernelGGL(latent_ode_v14, dim3(64), dim3(256), 0, stream,
                     z0, tt, cond, W0, b0, g0, be0, W1, b1, g1, be1,
                     W2, b2, g2, be2, Wo, bo, out);
}